// Round 2
// baseline (113.122 us; speedup 1.0000x reference)
//
#include <hip/hip_runtime.h>
#include <cmath>

#define HH  64
#define WW  96
#define CC  128
#define BB  2
#define HWH (HH*WW)

#define PXB 16     // pixels (x) per block
#define NJ  10     // patch grid rows
#define NT  160    // threads = PXB * NJ
#define TR  20     // staged rows: [y-9, y+10]
#define TC  52     // staged cols: [X-12, X+40)
#define CK  16     // channels per chunk
#define NCHUNK 8   // 128 / 16
#define I1P 132    // padded I1 channel stride

typedef __attribute__((ext_vector_type(4))) _Float16 half4;

__global__ __launch_bounds__(NT) void corr_kernel(
    const float* __restrict__ I1,
    const float* __restrict__ I2,
    const float* __restrict__ flow,
    float* __restrict__ out)
{
    __shared__ __align__(16) unsigned char smem[TR*TC*CK*2 + PXB*I1P*4];
    _Float16* tile = (_Float16*)smem;                 // [CK][TR][TC] fp16, 33280 B
    float*    i1s  = (float*)(smem + TR*TC*CK*2);     // [PXB][I1P] f32,  8448 B
    float*    accs = (float*)smem;                    // alias (after compute): [NJ][PXB][20]

    const int tid = threadIdx.x;
    const int px  = tid & 15;
    const int j   = tid >> 4;            // 0..9
    const int X = blockIdx.x * PXB;
    const int y = blockIdx.y;
    const int b = blockIdx.z;
    const int x = X + px;

    const float cx = (float)x + flow[((b*2+0)*HH + y)*WW + x];
    const float cy = (float)y + flow[((b*2+1)*HH + y)*WW + x];
    const int x0c = (int)floorf(cx);
    const int y0c = (int)floorf(cy);

    // 16-col aligned window [s_img, s_img+15] covering valid cols x0c-4..x0c+5
    const int s_img = min(max((x0c - 4) & ~3, 0), WW - 16);
    const int o_off = (x0c - 4) - s_img;
    // window position inside the staged tile (clamped: outliers read valid-but-wrong
    // LDS slots whose outputs are fully masked by vx/vy below)
    const int w  = min(max(s_img - (X - 12), 0), TC - 16);
    const int y0cl = min(max(y0c, y - 5), y + 4);
    const int rr   = y0cl - y + 5 + j;   // tile row for this thread, in [0,18]

    // ---- stage I1 tile: [px][c] fp32, padded stride ----
    for (int i = 0; i < 13; ++i) {
        int e = tid + i * NT;
        if (e < CC * PXB) {
            int c = e >> 4, p = e & 15;
            i1s[p * I1P + c] = I1[((size_t)(b*CC + c)*HH + y)*WW + X + p];
        }
    }

    float acc[16];
#pragma unroll
    for (int k = 0; k < 16; ++k) acc[k] = 0.f;

    for (int ch = 0; ch < NCHUNK; ++ch) {
        __syncthreads();
        // ---- stage I2 chunk: CK channels x TR rows x 13 float4 (52 cols) ----
        for (int i = 0; i < 26; ++i) {
            unsigned sl = (unsigned)(tid + i * NT);      // < 4160
            unsigned c  = sl / 260u;
            unsigned rem = sl - c * 260u;
            unsigned r  = rem / 13u;
            unsigned q4 = rem - r * 13u;
            int row = min(max(y - 9 + (int)r, 0), HH - 1);
            int col = max(min(X - 12 + (int)q4 * 4, WW - 4), 0);
            const float4 v = *(const float4*)&I2[((size_t)(b*CC + ch*CK + c)*HH + row)*WW + col];
            half4 hv = { (_Float16)v.x, (_Float16)v.y, (_Float16)v.z, (_Float16)v.w };
            *(half4*)&tile[(c*TR + r)*TC + q4*4] = hv;
        }
        __syncthreads();

        // ---- compute: 16 channels, 16-col window in registers ----
        const float4* ap = (const float4*)&i1s[px * I1P + ch * CK];
#pragma unroll
        for (int c4 = 0; c4 < 4; ++c4) {
            const float4 a4 = ap[c4];
            const float av[4] = { a4.x, a4.y, a4.z, a4.w };
#pragma unroll
            for (int q = 0; q < 4; ++q) {
                const float a = av[q];
                const _Float16* tp = &tile[(((c4*4 + q)*TR) + rr)*TC + w];
                const half4 h0 = *(const half4*)(tp + 0);
                const half4 h1 = *(const half4*)(tp + 4);
                const half4 h2 = *(const half4*)(tp + 8);
                const half4 h3 = *(const half4*)(tp + 12);
                acc[0]  += a * (float)h0[0];  acc[1]  += a * (float)h0[1];
                acc[2]  += a * (float)h0[2];  acc[3]  += a * (float)h0[3];
                acc[4]  += a * (float)h1[0];  acc[5]  += a * (float)h1[1];
                acc[6]  += a * (float)h1[2];  acc[7]  += a * (float)h1[3];
                acc[8]  += a * (float)h2[0];  acc[9]  += a * (float)h2[1];
                acc[10] += a * (float)h2[2];  acc[11] += a * (float)h2[3];
                acc[12] += a * (float)h3[0];  acc[13] += a * (float)h3[1];
                acc[14] += a * (float)h3[2];  acc[15] += a * (float)h3[3];
            }
        }
    }

    __syncthreads();
    // ---- dump D-grid to LDS (alias over tile) ----
#pragma unroll
    for (int k = 0; k < 16; ++k) accs[(j*PXB + px)*20 + k] = acc[k];
    __syncthreads();

    // ---- combine: 81 outputs per pixel from shared bilinear weights ----
    const float wx1 = cx - (float)x0c, wx0 = 1.f - wx1;
    const float wy1 = cy - (float)y0c, wy0 = 1.f - wy1;
    float* outb = out + (size_t)b * 81 * HWH + (y*WW + x);

#pragma unroll
    for (int k = 0; k < 9; ++k) {
        const int o = j + 10*k;
        if (o < 81) {
            const int dyi = o / 9;
            const int dxi = o - dyi*9;
            const int ix0 = x0c - 4 + dxi;
            const int iy0 = y0c - 4 + dyi;
            const bool vx0 = (ix0   >= 0) && (ix0   < WW);
            const bool vx1 = (ix0+1 >= 0) && (ix0+1 < WW);
            const bool vy0 = (iy0   >= 0) && (iy0   < HH);
            const bool vy1 = (iy0+1 >= 0) && (iy0+1 < HH);
            const int i0 = min(max(o_off + dxi,     0), 15);
            const int i1 = min(max(o_off + dxi + 1, 0), 15);
            const float d00 = accs[(dyi    *PXB + px)*20 + i0];
            const float d01 = accs[(dyi    *PXB + px)*20 + i1];
            const float d10 = accs[((dyi+1)*PXB + px)*20 + i0];
            const float d11 = accs[((dyi+1)*PXB + px)*20 + i1];
            const float r0 = (vx0 ? wx0*d00 : 0.f) + (vx1 ? wx1*d01 : 0.f);
            const float r1 = (vx0 ? wx0*d10 : 0.f) + (vx1 ? wx1*d11 : 0.f);
            const float v  = (vy0 ? wy0*r0 : 0.f) + (vy1 ? wy1*r1 : 0.f);
            outb[(size_t)o * HWH] = v;
        }
    }
}

extern "C" void kernel_launch(void* const* d_in, const int* in_sizes, int n_in,
                              void* d_out, int out_size, void* d_ws, size_t ws_size,
                              hipStream_t stream)
{
    const float* I1   = (const float*)d_in[0];
    const float* I2   = (const float*)d_in[1];
    const float* flow = (const float*)d_in[2];
    float* out = (float*)d_out;

    dim3 grid(WW/PXB, HH, BB);
    corr_kernel<<<grid, dim3(NT), 0, stream>>>(I1, I2, flow, out);
}

// Round 3
// 76.994 us; speedup vs baseline: 1.4692x; 1.4692x over previous
//
#include <hip/hip_runtime.h>
#include <cmath>

#define HH  64
#define WW  96
#define CC  128
#define BB  2
#define HWI (HH*WW)

#define PXB 16     // pixels per block (M)
#define TRR 20     // staged tile rows   [y-9, y+10]
#define TCC 48     // staged tile cols   [X-12, X+36)
#define NT  384    // 6 waves
#define TPW 10     // N-tiles per wave (60 total = 20r x 3ct)

typedef __attribute__((ext_vector_type(8))) _Float16 half8;
typedef __attribute__((ext_vector_type(4))) float    f32x4;

// LDS map (64 KiB total):
//   B tile  bytes [0, 61440):  fp16 [r=20][c=48][ch=32], 64B channel-line,
//           swizzle: byte ^= ((c&7)<<4)   (bijective; spreads col-stride off bank 0)
//   A tile  bytes [61440, 65536): fp16 [px=16][ch=128], swizzle byte ^= ((px&7)<<4)
//   accs    (aliases B after compute): f32 [r=20][px=16][c=48]

__global__ __launch_bounds__(NT) void corr_kernel(
    const float* __restrict__ I1,
    const float* __restrict__ I2,
    const float* __restrict__ flow,
    float* __restrict__ out)
{
    __shared__ __align__(16) unsigned char smem[65536];
    unsigned char* Alds = smem + 61440;

    const int tid  = threadIdx.x;
    const int lane = tid & 63;
    const int wid  = tid >> 6;

    const int X = blockIdx.x * PXB;
    const int y = blockIdx.y;
    const int b = blockIdx.z;

    // ---------------- stage A: I1[ch][y][X..X+15] -> fp16, swizzled ----------------
    {
        const int apx = tid & 15;
        const int swz = (apx & 7) << 4;
#pragma unroll
        for (int i = 0; i < 3; ++i) {
            const int kp = (tid >> 4) + 24 * i;     // ch-pair 0..71 (<64 valid)
            if (kp < 64) {
                const int ch = kp * 2;
                const float f0 = I1[((size_t)(b*CC + ch    )*HH + y)*WW + X + apx];
                const float f1 = I1[((size_t)(b*CC + ch + 1)*HH + y)*WW + X + apx];
                const unsigned int h0 = __builtin_bit_cast(unsigned short, (_Float16)f0);
                const unsigned int h1 = __builtin_bit_cast(unsigned short, (_Float16)f1);
                const int byte = (apx*256 + (kp >> 2)*16 + (kp & 3)*4) ^ swz;
                *(unsigned int*)(Alds + byte) = h0 | (h1 << 16);
            }
        }
    }

    // ---------------- staging roles (div-free, fixed per thread) ----------------
    const int kp  = tid & 15;          // ch-pair within 32-ch chunk
    const int q   = tid >> 4;          // 0..23
    const int c4  = q % 12;            // float4-column group
    const int rb  = q / 12;            // row base (0/1)
    const int gcb = min(max(X - 12 + c4*4, 0), WW - 4);   // clamped, 16B-aligned
    const int wbase = (kp >> 2)*16 + (kp & 3)*4;          // within 64B channel-line

    // ---------------- fragment address pieces ----------------
    const int g   = lane >> 4;         // k-group 0..3
    const int fpx = lane & 15;         // A: m | B: n
    const int bfrag_base = ((fpx*64 + g*16) ^ ((fpx & 7) << 4)); // + r*3072 + ct*1024
    const int abase = fpx*256 + g*16;                            // + kc*64, then ^swzA
    const int swzA  = (fpx & 7) << 4;

    f32x4 acc[TPW];
#pragma unroll
    for (int t = 0; t < TPW; ++t) acc[t] = (f32x4){0.f, 0.f, 0.f, 0.f};

    for (int kc = 0; kc < 4; ++kc) {
        __syncthreads();
        // ---- stage B chunk: 32 ch of I2 rows [y-9,y+10], cols [X-12,X+36) ----
        {
            const int ch = kc*32 + kp*2;
            const float* gsrc = I2 + (size_t)(b*CC + ch)*HWI + gcb;
#pragma unroll
            for (int i = 0; i < 10; ++i) {
                const int r    = rb + 2*i;
                const int grow = min(max(y - 9 + r, 0), HH - 1);
                const float4 v0 = *(const float4*)(gsrc + (size_t)grow*WW);
                const float4 v1 = *(const float4*)(gsrc + (size_t)grow*WW + HWI);
                const float e0[4] = {v0.x, v0.y, v0.z, v0.w};
                const float e1[4] = {v1.x, v1.y, v1.z, v1.w};
                const int rbyte = r*3072;
#pragma unroll
                for (int w = 0; w < 4; ++w) {
                    const int c = c4*4 + w;
                    const unsigned int h0 = __builtin_bit_cast(unsigned short, (_Float16)e0[w]);
                    const unsigned int h1 = __builtin_bit_cast(unsigned short, (_Float16)e1[w]);
                    const int byte = (rbyte + c*64 + wbase) ^ ((c & 7) << 4);
                    *(unsigned int*)(smem + byte) = h0 | (h1 << 16);
                }
            }
        }
        __syncthreads();

        // ---- compute: A-frag once, 10 B-frag + MFMA per wave ----
        const half8 af = *(const half8*)(Alds + ((abase + kc*64) ^ swzA));
#pragma unroll
        for (int tt = 0; tt < TPW; ++tt) {
            const int t  = wid*TPW + tt;
            const int r  = t / 3;
            const int ct = t - r*3;
            const half8 bf = *(const half8*)(smem + (r*3072 + ct*1024 + bfrag_base));
            acc[tt] = __builtin_amdgcn_mfma_f32_16x16x32_f16(af, bf, acc[tt], 0, 0, 0);
        }
    }

    // ---------------- dump D-grid: acc -> LDS f32 [r][px][48] ----------------
    __syncthreads();
    float* accs = (float*)smem;
#pragma unroll
    for (int tt = 0; tt < TPW; ++tt) {
        const int t  = wid*TPW + tt;
        const int r  = t / 3;
        const int ct = t - r*3;
        const int c  = ct*16 + fpx;
#pragma unroll
        for (int rg = 0; rg < 4; ++rg) {
            const int px = g*4 + rg;                  // C/D: row = (lane>>4)*4 + reg
            accs[(r*16 + px)*48 + c] = acc[tt][rg];   // col = lane&15
        }
    }
    __syncthreads();

    // ---------------- combine: 81 outputs/pixel, shared bilinear weights ----------------
    const int px = tid & 15;
    const int gq = tid >> 4;                          // 0..23
    const int x  = X + px;
    const float cx = (float)x + flow[((size_t)(b*2+0)*HH + y)*WW + x];
    const float cy = (float)y + flow[((size_t)(b*2+1)*HH + y)*WW + x];
    const int x0c = (int)floorf(cx);
    const int y0c = (int)floorf(cy);
    const int s_img = min(max((x0c - 4) & ~3, 0), WW - 16);
    const int o_off = (x0c - 4) - s_img;
    const int wcol  = s_img - (X - 12);
    const float wx1 = cx - (float)x0c, wx0 = 1.f - wx1;
    const float wy1 = cy - (float)y0c, wy0 = 1.f - wy1;
    float* outb = out + (size_t)b*81*HWI + (size_t)y*WW + x;

#pragma unroll
    for (int k = 0; k < 4; ++k) {
        const int o = gq + 24*k;
        if (o < 81) {
            const int dyi = o / 9;
            const int dxi = o - dyi*9;
            const int ix0 = x0c - 4 + dxi;
            const int iy0 = y0c - 4 + dyi;
            const bool vx0 = (ix0   >= 0) && (ix0   < WW);
            const bool vx1 = (ix0+1 >= 0) && (ix0+1 < WW);
            const bool vy0 = (iy0   >= 0) && (iy0   < HH);
            const bool vy1 = (iy0+1 >= 0) && (iy0+1 < HH);
            const int rt = min(max(y0c - y + 5 + dyi, 0), TRR - 2);   // 0..18
            const int c0 = min(max(wcol + o_off + dxi, 0), TCC - 2);  // == ix0-(X-12) in-range
            const float d00 = accs[(rt    *16 + px)*48 + c0];
            const float d01 = accs[(rt    *16 + px)*48 + c0 + 1];
            const float d10 = accs[((rt+1)*16 + px)*48 + c0];
            const float d11 = accs[((rt+1)*16 + px)*48 + c0 + 1];
            const float r0 = (vx0 ? wx0*d00 : 0.f) + (vx1 ? wx1*d01 : 0.f);
            const float r1 = (vx0 ? wx0*d10 : 0.f) + (vx1 ? wx1*d11 : 0.f);
            const float v  = (vy0 ? wy0*r0 : 0.f) + (vy1 ? wy1*r1 : 0.f);
            outb[(size_t)o * HWI] = v;
        }
    }
}

extern "C" void kernel_launch(void* const* d_in, const int* in_sizes, int n_in,
                              void* d_out, int out_size, void* d_ws, size_t ws_size,
                              hipStream_t stream)
{
    const float* I1   = (const float*)d_in[0];
    const float* I2   = (const float*)d_in[1];
    const float* flow = (const float*)d_in[2];
    float* out = (float*)d_out;

    dim3 grid(WW/PXB, HH, BB);
    corr_kernel<<<grid, dim3(NT), 0, stream>>>(I1, I2, flow, out);
}

// Round 4
// 35.858 us; speedup vs baseline: 3.1548x; 2.1472x over previous
//
#include <hip/hip_runtime.h>

#define HH  64
#define WW  96
#define CC  128
#define BB  2
#define HWI (HH*WW)

#define TRR 20          // staged rows [y0-9, y0+10]
#define TCC 48          // staged cols [s_tile, s_tile+48)
#define AOFF 61440      // B tile bytes [0,61440); A at [61440, 61440+8704)

typedef __attribute__((ext_vector_type(8))) _Float16 half8;
typedef __attribute__((ext_vector_type(4))) float    f32x4;
typedef unsigned int u32;

__device__ __forceinline__ void gll16(const void* g, void* l) {
    __builtin_amdgcn_global_load_lds(
        (const __attribute__((address_space(1))) u32*)g,
        (__attribute__((address_space(3))) u32*)l, 16, 0, 0);
}

// ---- prologue: I2 fp32 [b][ch][h][w] -> I2t fp16 [b][kc][row][col][32ch],
//      granule g (8 ch) baked at slot g^(col&3) within each 64B line ----
__global__ __launch_bounds__(256) void conv_i2(const float* __restrict__ I2,
                                               _Float16* __restrict__ I2t)
{
    const int idx  = blockIdx.x*256 + threadIdx.x;   // 196608 = 2*4*64*96*4
    const int g    = idx & 3;
    const int line = idx >> 2;
    const int col  = line % WW;
    int t = line / WW;
    const int row = t % HH;  t /= HH;
    const int kc  = t & 3;
    const int b   = t >> 2;
    const float* src = I2 + ((size_t)(b*CC + kc*32 + g*8)*HH + row)*WW + col;
    half8 h;
#pragma unroll
    for (int j = 0; j < 8; ++j) h[j] = (_Float16)src[(size_t)j*HWI];
    *(half8*)(I2t + (size_t)line*32 + (g ^ (col & 3))*8) = h;
}

// ---- main: per block 16px x 2rows; D-grid via MFMA; combine bilinear ----
__global__ __launch_bounds__(512, 4) void corr_kernel(
    const float* __restrict__ I1,
    const _Float16* __restrict__ I2t,
    const float* __restrict__ flow,
    float* __restrict__ out)
{
    __shared__ __align__(16) unsigned char smem[70144];

    const int tid  = threadIdx.x;
    const int lane = tid & 63;
    const int w    = tid >> 6;
    const int X  = blockIdx.x * 16;
    const int y0 = blockIdx.y * 2;
    const int b  = blockIdx.z;
    const int s_tile = min(max(X - 12, 0), WW - TCC);

    const int fpx = lane & 15;
    const int kg  = lane >> 4;
    const int my  = w & 1;        // M-tile (yloc)
    const int nw  = w >> 1;       // n-tile lane group

    // ---- stage A in-kernel: fp16 [my2][px16][ch128], stride 272B ----
    {
        _Float16* A = (_Float16*)(smem + AOFF);
#pragma unroll
        for (int i = 0; i < 8; ++i) {
            const int e   = tid + 512*i;        // 0..4095
            const int apx = e & 15;
            const int ch  = (e >> 4) & 127;
            const int myy = e >> 11;
            const float v = I1[((size_t)(b*CC + ch)*HH + y0 + myy)*WW + X + apx];
            *(_Float16*)((char*)A + (myy*16 + apx)*272 + ch*2) = (_Float16)v;
        }
    }

    // ---- async B staging (global_load_lds, 60 x 1KB per round) ----
    auto stageB = [&](int kc) {
#pragma unroll
        for (int i = 0; i < 8; ++i) {
            const int idx = w + 8*i;
            if (idx < 60) {
                const int r_t  = idx / 3;
                const int part = idx - r_t*3;
                const int grow = min(max(y0 - 9 + r_t, 0), HH - 1);
                const char* src = (const char*)I2t
                    + (size_t)((b*4 + kc)*HH + grow)*6144 + s_tile*64
                    + part*1024 + lane*16;
                gll16(src, smem + r_t*3072 + part*1024);
            }
        }
    };

    // hoisted B-fragment LDS offsets (kc-independent)
    int boff[15];
#pragma unroll
    for (int i = 0; i < 15; ++i) {
        const int n   = (nw + 4*i)*16 + fpx;
        const int r_t = n / 48;
        const int c_t = n - r_t*48;
        boff[i] = r_t*3072 + c_t*64 + ((kg ^ ((s_tile + c_t) & 3)) << 4);
    }

    f32x4 acc[15];
#pragma unroll
    for (int i = 0; i < 15; ++i) acc[i] = (f32x4){0.f,0.f,0.f,0.f};

    stageB(0);
    __syncthreads();

    for (int kc = 0; kc < 4; ++kc) {
        const half8 af = *(const half8*)(smem + AOFF + (my*16 + fpx)*272 + kc*64 + (kg << 4));
#pragma unroll
        for (int i = 0; i < 15; ++i) {
            const half8 bf = *(const half8*)(smem + boff[i]);
            acc[i] = __builtin_amdgcn_mfma_f32_16x16x32_f16(af, bf, acc[i], 0, 0, 0);
        }
        __syncthreads();
        if (kc < 3) {
            stageB(kc + 1);
            __syncthreads();
        }
    }

    // ---- epilogue: per yloc {dump D fp32 [20][16][49], combine} ----
    float* D = (float*)smem;
    const int px = tid & 15;
    const int oq = tid >> 4;   // 0..31

    for (int yloc = 0; yloc < 2; ++yloc) {
        if (my == yloc) {
#pragma unroll
            for (int i = 0; i < 15; ++i) {
                const int n   = (nw + 4*i)*16 + fpx;
                const int r_t = n / 48;
                const int c_t = n - r_t*48;
#pragma unroll
                for (int rg = 0; rg < 4; ++rg)
                    D[(r_t*16 + kg*4 + rg)*49 + c_t] = acc[i][rg];
            }
        }
        __syncthreads();

        const int yy = y0 + yloc;
        const int xx = X + px;
        const float cx = (float)xx + flow[((size_t)(b*2+0)*HH + yy)*WW + xx];
        const float cy = (float)yy + flow[((size_t)(b*2+1)*HH + yy)*WW + xx];
        const int x0c = (int)floorf(cx);
        const int y0c = (int)floorf(cy);
        const float wx1 = cx - (float)x0c, wx0 = 1.f - wx1;
        const float wy1 = cy - (float)y0c, wy0 = 1.f - wy1;
        float* outb = out + (size_t)b*81*HWI + (size_t)yy*WW + xx;

#pragma unroll
        for (int k = 0; k < 3; ++k) {
            const int o = oq + 32*k;
            if (o < 81) {
                const int dyi = o / 9;
                const int dxi = o - dyi*9;
                const int ix0 = x0c - 4 + dxi;
                const int iy0 = y0c - 4 + dyi;
                const bool vx0 = (ix0   >= 0) && (ix0   < WW);
                const bool vx1 = (ix0+1 >= 0) && (ix0+1 < WW);
                const bool vy0 = (iy0   >= 0) && (iy0   < HH);
                const bool vy1 = (iy0+1 >= 0) && (iy0+1 < HH);
                const int rt  = iy0 - y0 + 9;
                const int r0c = min(max(rt,     0), 19);
                const int r1c = min(max(rt + 1, 0), 19);
                const int c0  = ix0 - s_tile;
                const int c0c = min(max(c0,     0), 47);
                const int c1c = min(max(c0 + 1, 0), 47);
                const float d00 = D[(r0c*16 + px)*49 + c0c];
                const float d01 = D[(r0c*16 + px)*49 + c1c];
                const float d10 = D[(r1c*16 + px)*49 + c0c];
                const float d11 = D[(r1c*16 + px)*49 + c1c];
                const float r0 = (vx0 ? wx0*d00 : 0.f) + (vx1 ? wx1*d01 : 0.f);
                const float r1 = (vx0 ? wx0*d10 : 0.f) + (vx1 ? wx1*d11 : 0.f);
                const float v  = (vy0 ? wy0*r0 : 0.f) + (vy1 ? wy1*r1 : 0.f);
                outb[(size_t)o*HWI] = v;
            }
        }
        __syncthreads();
    }
}

extern "C" void kernel_launch(void* const* d_in, const int* in_sizes, int n_in,
                              void* d_out, int out_size, void* d_ws, size_t ws_size,
                              hipStream_t stream)
{
    const float* I1   = (const float*)d_in[0];
    const float* I2   = (const float*)d_in[1];
    const float* flow = (const float*)d_in[2];
    float* out = (float*)d_out;
    _Float16* I2t = (_Float16*)d_ws;   // 3,145,728 B

    conv_i2<<<dim3(768), dim3(256), 0, stream>>>(I2, I2t);
    corr_kernel<<<dim3(WW/16, HH/2, BB), dim3(512), 0, stream>>>(I1, I2t, flow, out);
}

// Round 6
// 31.897 us; speedup vs baseline: 3.5465x; 1.1242x over previous
//
#include <hip/hip_runtime.h>

#define HH  64
#define WW  96
#define CC  128
#define BB  2
#define HWI (HH*WW)

#define TCC  48          // staged cols [s_tile, s_tile+48)
#define BUFB 30720       // one 16-ch round buffer: 20 rows * 48 cols * 32 B
#define AOFF 61440       // A tile after the two B buffers
#define LDSZ 70144       // 2*BUFB + 2*16*272

typedef __attribute__((ext_vector_type(4))) _Float16 half4;
typedef __attribute__((ext_vector_type(8))) _Float16 half8;
typedef __attribute__((ext_vector_type(4))) float    f32x4;
typedef unsigned int u32;

__device__ __forceinline__ void gll16(const void* g, void* l) {
    __builtin_amdgcn_global_load_lds(
        (const __attribute__((address_space(1))) u32*)g,
        (__attribute__((address_space(3))) u32*)l, 16, 0, 0);   // width 16: HW-verified
}

// K=16 MFMA; fallback = K=32 MFMA with zero-padded upper k-slots (slot-aligned
// zeros contribute 0 to the dot — correct regardless of k-label convention).
__device__ __forceinline__ f32x4 mfma16(half4 a, half4 b, f32x4 c) {
#if __has_builtin(__builtin_amdgcn_mfma_f32_16x16x16f16)
    return __builtin_amdgcn_mfma_f32_16x16x16f16(a, b, c, 0, 0, 0);
#else
    const _Float16 z = (_Float16)0.f;
    const half8 a8 = { a[0], a[1], a[2], a[3], z, z, z, z };
    const half8 b8 = { b[0], b[1], b[2], b[3], z, z, z, z };
    return __builtin_amdgcn_mfma_f32_16x16x32_f16(a8, b8, c, 0, 0, 0);
#endif
}

// ---- prologue: I2 fp32 [b][ch][h][w] -> I2t fp16 [b][kc16][row][col][4 quad-slots x 8B]
//      quad q (4 ch) baked at slot q ^ ((col>>2)&3)  (bank-spread for b64 frag reads) ----
__global__ __launch_bounds__(256) void conv_i2(const float* __restrict__ I2,
                                               unsigned char* __restrict__ I2t)
{
    const int idx = blockIdx.x*256 + threadIdx.x;   // 196608 = 2*8*64*96*2
    const int gh  = idx & 1;                        // ch-octet within 16-ch chunk
    const int L   = idx >> 1;                       // line = ((b*8+kc)*64+row)*96+col
    const int col = L % WW;
    int t = L / WW;
    const int row = t & 63;  t >>= 6;
    const int kc  = t & 7;
    const int b   = t >> 3;
    const int s   = (col >> 2) & 3;

    const float* src = I2 + ((size_t)(b*CC + kc*16 + gh*8)*HH + row)*WW + col;
    _Float16 h[8];
#pragma unroll
    for (int j = 0; j < 8; ++j) h[j] = (_Float16)src[(size_t)j*HWI];

    unsigned char* line = I2t + (size_t)L*32;
    half4 q0 = { h[0], h[1], h[2], h[3] };
    half4 q1 = { h[4], h[5], h[6], h[7] };
    *(half4*)(line + (((2*gh    ) ^ s) << 3)) = q0;
    *(half4*)(line + (((2*gh + 1) ^ s) << 3)) = q1;
}

// ---- main: 16px x 2rows per block; 2-phase dbuf staging (plain __syncthreads);
//      D-grid via MFMA; combine bilinear (R4-verified epilogue) ----
__global__ __launch_bounds__(512, 4) void corr_kernel(
    const float* __restrict__ I1,
    const unsigned char* __restrict__ I2t,
    const float* __restrict__ flow,
    float* __restrict__ out)
{
    __shared__ __align__(16) unsigned char smem[LDSZ];

    const int tid  = threadIdx.x;
    const int lane = tid & 63;
    const int w    = tid >> 6;
    const int X  = blockIdx.x * 16;
    const int y0 = blockIdx.y * 2;
    const int b  = blockIdx.z;
    const int s_tile = min(max(X - 12, 0), WW - TCC);

    const int fpx = lane & 15;
    const int kg  = lane >> 4;
    const int my  = w & 1;        // M-tile (yloc)
    const int nw  = w >> 1;       // n-tile lane group

    // ---- stage A in-kernel: fp16 [my2][px16][ch128], stride 272B ----
    {
#pragma unroll
        for (int i = 0; i < 8; ++i) {
            const int e   = tid + 512*i;        // 0..4095
            const int apx = e & 15;
            const int ch  = (e >> 4) & 127;
            const int myy = e >> 11;
            const float v = I1[((size_t)(b*CC + ch)*HH + y0 + myy)*WW + X + apx];
            *(_Float16*)(smem + AOFF + (myy*16 + apx)*272 + ch*2) = (_Float16)v;
        }
    }

    // ---- hoisted B-fragment offsets (buffer-relative) ----
    int boff[15];
#pragma unroll
    for (int i = 0; i < 15; ++i) {
        const int n   = (nw + 4*i)*16 + fpx;
        const int r_t = n / 48;
        const int c_t = n - r_t*48;
        boff[i] = r_t*1536 + c_t*32 + ((kg ^ (((s_tile + c_t) >> 2) & 3)) << 3);
    }
    const int aoff = AOFF + (my*16 + fpx)*272 + (kg << 3);

    // ---- async staging: round rr (16 ch) -> buffer cur; 30 x 1KB wide DMAs ----
    // LDS dest is wave-uniform + linear (lane*16 implicit); global src is per-lane,
    // so chunks that straddle a (clamped) row boundary are handled per-lane.
    auto stage = [&](int rr, int cur) {
#pragma unroll
        for (int i = 0; i < 4; ++i) {
            const int p = w + 8*i;              // 0..31
            if (p < 30) {                       // wave-uniform predicate
                const int z   = p*1024 + lane*16;   // byte offset in round buffer
                const int r_t = z / 1536;           // tile row 0..19
                const int off = z - r_t*1536;       // col*32 + quad-byte
                const int c   = off >> 5;
                const int qb  = off & 31;           // 0 or 16
                const int grow = min(max(y0 - 9 + r_t, 0), HH - 1);
                const unsigned char* src = I2t
                    + ((size_t)(((b*8 + rr)*HH + grow)*WW + s_tile + c))*32 + qb;
                gll16(src, smem + cur*BUFB + p*1024);
            }
        }
    };

    f32x4 acc[15];
#pragma unroll
    for (int i = 0; i < 15; ++i) acc[i] = (f32x4){0.f,0.f,0.f,0.f};

    stage(0, 0);
    __syncthreads();                 // A visible + DMA(0) drained (vmcnt0 + lgkm0)

#pragma unroll
    for (int r = 0; r < 8; ++r) {
        const int cur = r & 1;
        if (r < 7) stage(r + 1, cur ^ 1);       // DMA flies under this round's compute
        const half4 af = *(const half4*)(smem + aoff + r*32);
#pragma unroll
        for (int i = 0; i < 15; ++i) {
            const half4 bf = *(const half4*)(smem + cur*BUFB + boff[i]);
            acc[i] = mfma16(af, bf, acc[i]);
        }
        __syncthreads();             // drains DMA(r+1); all reads of buf[cur] done
    }

    // ---- epilogue: per yloc {dump D fp32 [20][16][49], combine} (verified R4 math) ----
    float* D = (float*)smem;
    const int px = tid & 15;
    const int oq = tid >> 4;   // 0..31

    for (int yloc = 0; yloc < 2; ++yloc) {
        if (my == yloc) {
#pragma unroll
            for (int i = 0; i < 15; ++i) {
                const int n   = (nw + 4*i)*16 + fpx;
                const int r_t = n / 48;
                const int c_t = n - r_t*48;
#pragma unroll
                for (int rg = 0; rg < 4; ++rg)
                    D[(r_t*16 + kg*4 + rg)*49 + c_t] = acc[i][rg];
            }
        }
        __syncthreads();

        const int yy = y0 + yloc;
        const int xx = X + px;
        const float cx = (float)xx + flow[((size_t)(b*2+0)*HH + yy)*WW + xx];
        const float cy = (float)yy + flow[((size_t)(b*2+1)*HH + yy)*WW + xx];
        const int x0c = (int)floorf(cx);
        const int y0c = (int)floorf(cy);
        const float wx1 = cx - (float)x0c, wx0 = 1.f - wx1;
        const float wy1 = cy - (float)y0c, wy0 = 1.f - wy1;
        float* outb = out + (size_t)b*81*HWI + (size_t)yy*WW + xx;

#pragma unroll
        for (int k = 0; k < 3; ++k) {
            const int o = oq + 32*k;
            if (o < 81) {
                const int dyi = o / 9;
                const int dxi = o - dyi*9;
                const int ix0 = x0c - 4 + dxi;
                const int iy0 = y0c - 4 + dyi;
                const bool vx0 = (ix0   >= 0) && (ix0   < WW);
                const bool vx1 = (ix0+1 >= 0) && (ix0+1 < WW);
                const bool vy0 = (iy0   >= 0) && (iy0   < HH);
                const bool vy1 = (iy0+1 >= 0) && (iy0+1 < HH);
                const int rt  = iy0 - y0 + 9;
                const int r0c = min(max(rt,     0), 19);
                const int r1c = min(max(rt + 1, 0), 19);
                const int c0  = ix0 - s_tile;
                const int c0c = min(max(c0,     0), 47);
                const int c1c = min(max(c0 + 1, 0), 47);
                const float d00 = D[(r0c*16 + px)*49 + c0c];
                const float d01 = D[(r0c*16 + px)*49 + c1c];
                const float d10 = D[(r1c*16 + px)*49 + c0c];
                const float d11 = D[(r1c*16 + px)*49 + c1c];
                const float r0 = (vx0 ? wx0*d00 : 0.f) + (vx1 ? wx1*d01 : 0.f);
                const float r1 = (vx0 ? wx0*d10 : 0.f) + (vx1 ? wx1*d11 : 0.f);
                const float v  = (vy0 ? wy0*r0 : 0.f) + (vy1 ? wy1*r1 : 0.f);
                outb[(size_t)o*HWI] = v;
            }
        }
        __syncthreads();
    }
}

extern "C" void kernel_launch(void* const* d_in, const int* in_sizes, int n_in,
                              void* d_out, int out_size, void* d_ws, size_t ws_size,
                              hipStream_t stream)
{
    const float* I1   = (const float*)d_in[0];
    const float* I2   = (const float*)d_in[1];
    const float* flow = (const float*)d_in[2];
    float* out = (float*)d_out;
    unsigned char* I2t = (unsigned char*)d_ws;   // 3,145,728 B

    conv_i2<<<dim3(768), dim3(256), 0, stream>>>(I2, I2t);
    corr_kernel<<<dim3(WW/16, HH/2, BB), dim3(512), 0, stream>>>(I1, I2t, flow, out);
}

// Round 7
// 27.296 us; speedup vs baseline: 4.1442x; 1.1686x over previous
//
#include <hip/hip_runtime.h>

#define HH  64
#define WW  96
#define CC  128
#define BB  2
#define HWI (HH*WW)

#define TCOL 36          // staged cols [s_tile, s_tile+36) ⊇ needed [X-9, X+24]
#define ROWB (TCOL*64)   // 2304 B per staged row (36 cols x 64 B/32ch-line)
#define BUFB (20*ROWB)   // 46080 B = 45 x 1KB chunks exactly
#define NCHK 45
#define AOFF (2*BUFB)    // A tile after the two B buffers
#define ASTR 272         // A row stride (16B-aligned for b128 frag reads)
#define LDSZ (2*BUFB + 2*16*ASTR)   // 100,864 B -> 1 block/CU

typedef __attribute__((ext_vector_type(8))) _Float16 half8;
typedef __attribute__((ext_vector_type(4))) float    f32x4;
typedef unsigned int u32;

__device__ __forceinline__ void gll16(const void* g, void* l) {
    __builtin_amdgcn_global_load_lds(
        (const __attribute__((address_space(1))) u32*)g,
        (__attribute__((address_space(3))) u32*)l, 16, 0, 0);   // width 16: HW-verified
}

// ---- prologue: I2 fp32 [b][ch][h][w] -> I2t fp16 [b][kc32][row][col][4 granules x 16B]
//      granule g (8 ch, contiguous & in-order) at slot g ^ ((col ^ (col>>2)) & 3)
//      (R4-verified granule scheme; extra (col>>2) term kills 4-way frag-read conflicts) ----
__global__ __launch_bounds__(256) void conv_i2(const float* __restrict__ I2,
                                               unsigned char* __restrict__ I2t)
{
    const int idx = blockIdx.x*256 + threadIdx.x;   // 196608 = 2*4*64*96*4
    const int g   = idx & 3;                        // 8-ch granule within 32-ch line
    const int L   = idx >> 2;                       // line = ((b*4+kc)*64+row)*96+col
    const int col = L % WW;
    int t = L / WW;
    const int row = t & 63;  t >>= 6;
    const int kc  = t & 3;
    const int b   = t >> 2;
    const int slot = g ^ ((col ^ (col >> 2)) & 3);

    const float* src = I2 + ((size_t)(b*CC + kc*32 + g*8)*HH + row)*WW + col;
    half8 h;
#pragma unroll
    for (int j = 0; j < 8; ++j) h[j] = (_Float16)src[(size_t)j*HWI];
    *(half8*)(I2t + (size_t)L*64 + slot*16) = h;
}

// ---- main: 16px x 2rows per block; 4 rounds K32, 2-phase dbuf (plain __syncthreads);
//      fused fp16-D epilogue ----
__global__ __launch_bounds__(512) void corr_kernel(
    const float* __restrict__ I1,
    const unsigned char* __restrict__ I2t,
    const float* __restrict__ flow,
    float* __restrict__ out)
{
    __shared__ __align__(16) unsigned char smem[LDSZ];

    const int tid  = threadIdx.x;
    const int lane = tid & 63;
    const int w    = tid >> 6;
    const int X  = blockIdx.x * 16;
    const int y0 = blockIdx.y * 2;
    const int b  = blockIdx.z;
    const int s_tile = min(max(X - 10, 0), WW - TCOL);

    const int fpx = lane & 15;
    const int kg  = lane >> 4;
    const int my  = w & 1;        // M-tile (yloc)
    const int nw  = w >> 1;       // n-tile lane group

    // ---- stage A: fp16 [my2][px16][ch128], stride 272 B ----
    {
#pragma unroll
        for (int i = 0; i < 8; ++i) {
            const int e   = tid + 512*i;        // 0..4095
            const int apx = e & 15;
            const int ch  = (e >> 4) & 127;
            const int myy = e >> 11;
            const float v = I1[((size_t)(b*CC + ch)*HH + y0 + myy)*WW + X + apx];
            *(_Float16*)(smem + AOFF + (myy*16 + apx)*ASTR + ch*2) = (_Float16)v;
        }
    }

    // ---- hoisted B-fragment offsets (buffer-relative); 45 tiles over n = r*36+c ----
    int boff[12];
#pragma unroll
    for (int i = 0; i < 12; ++i) {
        const int n   = (nw + 4*i)*16 + fpx;
        const int r_t = n / 45 / 16 * 0 + n / TCOL;     // n/36
        const int c_t = n - r_t*TCOL;
        const int col = s_tile + c_t;
        boff[i] = r_t*ROWB + c_t*64 + ((kg ^ ((col ^ (col >> 2)) & 3)) << 4);
    }
    const int aoff = AOFF + (my*16 + fpx)*ASTR + (kg << 4);

    // ---- async staging: round rr (32 ch) -> buffer cur; 45 x 1KB DMA chunks ----
    auto stage = [&](int rr, int cur) {
#pragma unroll
        for (int i = 0; i < 6; ++i) {
            const int p = w + 8*i;              // 0..47, wave-uniform
            if (p < NCHK) {
                const int z   = p*1024 + lane*16;
                const int r_t = z / ROWB;           // staged row 0..19
                const int off = z - r_t*ROWB;
                const int c   = off >> 6;
                const int lb  = off & 63;           // 0/16/32/48
                const int grow = min(max(y0 - 9 + r_t, 0), HH - 1);
                const unsigned char* src = I2t
                    + ((size_t)(((b*4 + rr)*HH + grow)*WW + s_tile + c))*64 + lb;
                gll16(src, smem + cur*BUFB + p*1024);
            }
        }
    };

    f32x4 acc[12];
#pragma unroll
    for (int i = 0; i < 12; ++i) acc[i] = (f32x4){0.f,0.f,0.f,0.f};

    stage(0, 0);
    __syncthreads();                 // A visible + DMA(0) drained

#pragma unroll
    for (int r = 0; r < 4; ++r) {
        const int cur = r & 1;
        if (r < 3) stage(r + 1, cur ^ 1);       // DMA flies under this round's compute
        const half8 af = *(const half8*)(smem + aoff + r*64);
#pragma unroll
        for (int i = 0; i < 12; ++i) {
            if (nw + 4*i < NCHK) {              // wave-uniform tile-valid predicate
                const half8 bf = *(const half8*)(smem + cur*BUFB + boff[i]);
                acc[i] = __builtin_amdgcn_mfma_f32_16x16x32_f16(af, bf, acc[i], 0, 0, 0);
            }
        }
        __syncthreads();             // drains DMA(r+1); all reads of buf[cur] done
    }

    // ---- fused epilogue: dump BOTH ylocs' D as fp16 [2][20][16][40], one sync ----
    _Float16* D = (_Float16*)smem;
#pragma unroll
    for (int i = 0; i < 12; ++i) {
        if (nw + 4*i < NCHK) {
            const int n   = (nw + 4*i)*16 + fpx;
            const int r_t = n / TCOL;
            const int c_t = n - r_t*TCOL;
#pragma unroll
            for (int rg = 0; rg < 4; ++rg)
                D[((my*20 + r_t)*16 + kg*4 + rg)*40 + c_t] = (_Float16)acc[i][rg];
        }
    }
    __syncthreads();

    // ---- combine: 81 outputs/pixel x 2 rows, shared bilinear weights (R4 math) ----
    const int px = tid & 15;
    const int oq = tid >> 4;   // 0..31

#pragma unroll
    for (int yloc = 0; yloc < 2; ++yloc) {
        const int yy = y0 + yloc;
        const int xx = X + px;
        const float cx = (float)xx + flow[((size_t)(b*2+0)*HH + yy)*WW + xx];
        const float cy = (float)yy + flow[((size_t)(b*2+1)*HH + yy)*WW + xx];
        const int x0c = (int)floorf(cx);
        const int y0c = (int)floorf(cy);
        const float wx1 = cx - (float)x0c, wx0 = 1.f - wx1;
        const float wy1 = cy - (float)y0c, wy0 = 1.f - wy1;
        float* outb = out + (size_t)b*81*HWI + (size_t)yy*WW + xx;

#pragma unroll
        for (int k = 0; k < 3; ++k) {
            const int o = oq + 32*k;
            if (o < 81) {
                const int dyi = o / 9;
                const int dxi = o - dyi*9;
                const int ix0 = x0c - 4 + dxi;
                const int iy0 = y0c - 4 + dyi;
                const bool vx0 = (ix0   >= 0) && (ix0   < WW);
                const bool vx1 = (ix0+1 >= 0) && (ix0+1 < WW);
                const bool vy0 = (iy0   >= 0) && (iy0   < HH);
                const bool vy1 = (iy0+1 >= 0) && (iy0+1 < HH);
                const int rt  = iy0 - y0 + 9;
                const int r0c = min(max(rt,     0), 19);
                const int r1c = min(max(rt + 1, 0), 19);
                const int c0  = ix0 - s_tile;
                const int c0c = min(max(c0,     0), TCOL-1);
                const int c1c = min(max(c0 + 1, 0), TCOL-1);
                const float d00 = (float)D[((yloc*20 + r0c)*16 + px)*40 + c0c];
                const float d01 = (float)D[((yloc*20 + r0c)*16 + px)*40 + c1c];
                const float d10 = (float)D[((yloc*20 + r1c)*16 + px)*40 + c0c];
                const float d11 = (float)D[((yloc*20 + r1c)*16 + px)*40 + c1c];
                const float r0 = (vx0 ? wx0*d00 : 0.f) + (vx1 ? wx1*d01 : 0.f);
                const float r1 = (vx0 ? wx0*d10 : 0.f) + (vx1 ? wx1*d11 : 0.f);
                const float v  = (vy0 ? wy0*r0 : 0.f) + (vy1 ? wy1*r1 : 0.f);
                outb[(size_t)o*HWI] = v;
            }
        }
    }
}

extern "C" void kernel_launch(void* const* d_in, const int* in_sizes, int n_in,
                              void* d_out, int out_size, void* d_ws, size_t ws_size,
                              hipStream_t stream)
{
    const float* I1   = (const float*)d_in[0];
    const float* I2   = (const float*)d_in[1];
    const float* flow = (const float*)d_in[2];
    float* out = (float*)d_out;
    unsigned char* I2t = (unsigned char*)d_ws;   // 3,145,728 B

    conv_i2<<<dim3(768), dim3(256), 0, stream>>>(I2, I2t);
    corr_kernel<<<dim3(WW/16, HH/2, BB), dim3(512), 0, stream>>>(I1, I2t, flow, out);
}

// Round 8
// 25.892 us; speedup vs baseline: 4.3690x; 1.0542x over previous
//
#include <hip/hip_runtime.h>

#define HH  64
#define WW  96
#define CC  128
#define BB  2
#define HWI (HH*WW)

#define PXB  8           // pixels per block (x)
#define TCOL 28          // staged cols [s_tile, s_tile+28) ⊇ needed [X-9, X+17]
#define ROWB (TCOL*64)   // 1792 B per staged row
#define BUFB (20*ROWB)   // 35840 B = 35 x 1KB chunks exactly
#define NCHK 35          // DMA chunks / n-tiles per round
#define AOFF (2*BUFB)    // A tile after the two B buffers (71680)
#define ASTR 272         // A row stride (272B = 68 dw ≡ 4 mod 32: conflict-free frags)
#define LDSZ (AOFF + 16*ASTR)   // 76032 B -> 2 blocks/CU

typedef __attribute__((ext_vector_type(8))) _Float16 half8;
typedef __attribute__((ext_vector_type(4))) _Float16 half4;
typedef __attribute__((ext_vector_type(4))) float    f32x4;
typedef unsigned int u32;

__device__ __forceinline__ void gll16(const void* g, void* l) {
    __builtin_amdgcn_global_load_lds(
        (const __attribute__((address_space(1))) u32*)g,
        (__attribute__((address_space(3))) u32*)l, 16, 0, 0);   // width 16: HW-verified
}

// ---- prologue (verbatim R7): I2 fp32 -> I2t fp16 [b][kc32][row][col][4 granules x 16B]
//      granule g (8 ch) at slot g ^ ((col ^ (col>>2)) & 3) ----
__global__ __launch_bounds__(256) void conv_i2(const float* __restrict__ I2,
                                               unsigned char* __restrict__ I2t)
{
    const int idx = blockIdx.x*256 + threadIdx.x;   // 196608
    const int g   = idx & 3;
    const int L   = idx >> 2;                       // ((b*4+kc)*64+row)*96+col
    const int col = L % WW;
    int t = L / WW;
    const int row = t & 63;  t >>= 6;
    const int kc  = t & 3;
    const int b   = t >> 2;
    const int slot = g ^ ((col ^ (col >> 2)) & 3);

    const float* src = I2 + ((size_t)(b*CC + kc*32 + g*8)*HH + row)*WW + col;
    half8 h;
#pragma unroll
    for (int j = 0; j < 8; ++j) h[j] = (_Float16)src[(size_t)j*HWI];
    *(half8*)(I2t + (size_t)L*64 + slot*16) = h;
}

// ---- main: 8px x 2rows per block (M16 = yloc*8+px); 4 rounds K32, 2-phase dbuf ----
__global__ __launch_bounds__(256) void corr_kernel(
    const float* __restrict__ I1,
    const unsigned char* __restrict__ I2t,
    const float* __restrict__ flow,
    float* __restrict__ out)
{
    __shared__ __align__(16) unsigned char smem[LDSZ];

    const int tid  = threadIdx.x;
    const int lane = tid & 63;
    const int w    = tid >> 6;      // 4 waves
    const int X  = blockIdx.x * PXB;
    const int y0 = blockIdx.y * 2;
    const int b  = blockIdx.z;
    const int s_tile = min(max(X - 9, 0), WW - TCOL);

    const int fpx = lane & 15;      // MFMA n-lane / m-lane
    const int kg  = lane >> 4;      // k-group

    // ---- hoisted combine identity + flow loads (latency hides under staging) ----
    const int cpx = tid & 7;
    const int oq  = tid >> 3;       // 0..31
    const int xx  = X + cpx;
    float cxv[2], cyv[2];
#pragma unroll
    for (int yloc = 0; yloc < 2; ++yloc) {
        const int yy = y0 + yloc;
        cxv[yloc] = (float)xx + flow[((size_t)(b*2+0)*HH + yy)*WW + xx];
        cyv[yloc] = (float)yy + flow[((size_t)(b*2+1)*HH + yy)*WW + xx];
    }

    // ---- stage A: fp16 [m16][ch128] stride 272B, float4 I1 loads ----
#pragma unroll
    for (int i = 0; i < 2; ++i) {
        const int e   = tid + 256*i;        // 0..511
        const int q   = e & 1;
        const int ch  = (e >> 1) & 127;
        const int myy = e >> 8;
        const float4 v = *(const float4*)&I1[((size_t)(b*CC + ch)*HH + y0 + myy)*WW + X + q*4];
        const float ve[4] = { v.x, v.y, v.z, v.w };
#pragma unroll
        for (int k = 0; k < 4; ++k) {
            const int m = myy*8 + q*4 + k;
            *(_Float16*)(smem + AOFF + m*ASTR + ch*2) = (_Float16)ve[k];
        }
    }

    // ---- hoisted B-fragment offsets: n = r_t*28 + c_t over 35 tiles ----
    int boff[9];
#pragma unroll
    for (int i = 0; i < 9; ++i) {
        const int t   = min(w + 4*i, NCHK - 1);
        const int n   = t*16 + fpx;
        const int r_t = n / TCOL;
        const int c_t = n - r_t*TCOL;
        const int col = s_tile + c_t;
        boff[i] = r_t*ROWB + c_t*64 + ((kg ^ ((col ^ (col >> 2)) & 3)) << 4);
    }
    const int aoff = AOFF + fpx*ASTR + (kg << 4);

    // ---- async staging: round rr (32 ch) -> buffer cur; 35 x 1KB DMA chunks ----
    auto stage = [&](int rr, int cur) {
#pragma unroll
        for (int i = 0; i < 9; ++i) {
            const int p = w + 4*i;              // wave-uniform
            if (p < NCHK) {
                const int z   = p*1024 + lane*16;
                const int r_t = z / ROWB;           // staged row 0..19
                const int off = z - r_t*ROWB;
                const int c   = off >> 6;
                const int lb  = off & 63;
                const int grow = min(max(y0 - 9 + r_t, 0), HH - 1);
                const unsigned char* src = I2t
                    + ((size_t)(((b*4 + rr)*HH + grow)*WW + s_tile + c))*64 + lb;
                gll16(src, smem + cur*BUFB + p*1024);
            }
        }
    };

    f32x4 acc[9];
#pragma unroll
    for (int i = 0; i < 9; ++i) acc[i] = (f32x4){0.f,0.f,0.f,0.f};

    stage(0, 0);
    __syncthreads();                 // A visible + DMA(0) drained

#pragma unroll
    for (int r = 0; r < 4; ++r) {
        const int cur = r & 1;
        if (r < 3) stage(r + 1, cur ^ 1);       // DMA flies under this round's compute
        const half8 af = *(const half8*)(smem + aoff + r*64);
#pragma unroll
        for (int i = 0; i < 9; ++i) {
            if (w + 4*i < NCHK) {               // wave-uniform predicate
                const half8 bf = *(const half8*)(smem + cur*BUFB + boff[i]);
                acc[i] = __builtin_amdgcn_mfma_f32_16x16x32_f16(af, bf, acc[i], 0, 0, 0);
            }
        }
        __syncthreads();             // drains DMA(r+1); all reads of buf[cur] done
    }

    // ---- dump D fp16 [c28][r pad21][m pad20] via ds_write_b64 (conflict-free) ----
    _Float16* D = (_Float16*)smem;
#pragma unroll
    for (int i = 0; i < 9; ++i) {
        if (w + 4*i < NCHK) {
            const int n   = (w + 4*i)*16 + fpx;
            const int r_t = n / TCOL;
            const int c_t = n - r_t*TCOL;
            const half4 hv = { (_Float16)acc[i][0], (_Float16)acc[i][1],
                               (_Float16)acc[i][2], (_Float16)acc[i][3] };
            *(half4*)(D + (c_t*21 + r_t)*20 + kg*4) = hv;   // m = kg*4..kg*4+3
        }
    }
    __syncthreads();

    // ---- combine: 81 outputs x (8px, 2rows), shared bilinear weights (R4 math) ----
#pragma unroll
    for (int yloc = 0; yloc < 2; ++yloc) {
        const int yy = y0 + yloc;
        const int m  = yloc*8 + cpx;
        const float cx = cxv[yloc], cy = cyv[yloc];
        const int x0c = (int)floorf(cx);
        const int y0c = (int)floorf(cy);
        const float wx1 = cx - (float)x0c, wx0 = 1.f - wx1;
        const float wy1 = cy - (float)y0c, wy0 = 1.f - wy1;
        float* outb = out + (size_t)b*81*HWI + (size_t)yy*WW + xx;

#pragma unroll
        for (int k = 0; k < 3; ++k) {
            const int o = oq + 32*k;
            if (o < 81) {
                const int dyi = o / 9;
                const int dxi = o - dyi*9;
                const int ix0 = x0c - 4 + dxi;
                const int iy0 = y0c - 4 + dyi;
                const bool vx0 = (ix0   >= 0) && (ix0   < WW);
                const bool vx1 = (ix0+1 >= 0) && (ix0+1 < WW);
                const bool vy0 = (iy0   >= 0) && (iy0   < HH);
                const bool vy1 = (iy0+1 >= 0) && (iy0+1 < HH);
                const int rt  = iy0 - y0 + 9;
                const int r0c = min(max(rt,     0), 19);
                const int r1c = min(max(rt + 1, 0), 19);
                const int c0  = ix0 - s_tile;
                const int c0c = min(max(c0,     0), TCOL-1);
                const int c1c = min(max(c0 + 1, 0), TCOL-1);
                const float d00 = (float)D[(c0c*21 + r0c)*20 + m];
                const float d01 = (float)D[(c1c*21 + r0c)*20 + m];
                const float d10 = (float)D[(c0c*21 + r1c)*20 + m];
                const float d11 = (float)D[(c1c*21 + r1c)*20 + m];
                const float r0 = (vx0 ? wx0*d00 : 0.f) + (vx1 ? wx1*d01 : 0.f);
                const float r1 = (vx0 ? wx0*d10 : 0.f) + (vx1 ? wx1*d11 : 0.f);
                const float v  = (vy0 ? wy0*r0 : 0.f) + (vy1 ? wy1*r1 : 0.f);
                outb[(size_t)o*HWI] = v;
            }
        }
    }
}

extern "C" void kernel_launch(void* const* d_in, const int* in_sizes, int n_in,
                              void* d_out, int out_size, void* d_ws, size_t ws_size,
                              hipStream_t stream)
{
    const float* I1   = (const float*)d_in[0];
    const float* I2   = (const float*)d_in[1];
    const float* flow = (const float*)d_in[2];
    float* out = (float*)d_out;
    unsigned char* I2t = (unsigned char*)d_ws;   // 3,145,728 B

    conv_i2<<<dim3(768), dim3(256), 0, stream>>>(I2, I2t);
    corr_kernel<<<dim3(WW/PXB, HH/2, BB), dim3(256), 0, stream>>>(I1, I2t, flow, out);
}

// Round 9
// 24.713 us; speedup vs baseline: 4.5774x; 1.0477x over previous
//
#include <hip/hip_runtime.h>

#define HH  64
#define WW  96
#define CC  128
#define BB  2
#define HWI (HH*WW)

#define PXB  8           // pixels per block (x)
#define TCOL 28          // staged cols [s_tile, s_tile+28) ⊇ needed [X-9, X+17]
#define ROWB (TCOL*64)   // 1792 B per staged row
#define BUFB (20*ROWB)   // 35840 B = 35 x 1KB chunks exactly
#define NCHK 35          // DMA chunks / n-tiles per round
#define AOFF BUFB        // A tile after the single B buffer
#define ASTR 272         // A row stride
#define LDSZ (AOFF + 16*ASTR)   // 40192 B -> 4 blocks/CU capacity (768 all co-resident)

typedef __attribute__((ext_vector_type(8))) _Float16 half8;
typedef __attribute__((ext_vector_type(4))) _Float16 half4;
typedef __attribute__((ext_vector_type(4))) float    f32x4;
typedef unsigned int u32;

__device__ __forceinline__ void gll16(const void* g, void* l) {
    __builtin_amdgcn_global_load_lds(
        (const __attribute__((address_space(1))) u32*)g,
        (__attribute__((address_space(3))) u32*)l, 16, 0, 0);   // width 16: HW-verified
}

// ---- prologue (verbatim R7/R8): I2 fp32 -> I2t fp16 [b][kc32][row][col][4 granules x 16B]
//      granule g (8 ch) at slot g ^ ((col ^ (col>>2)) & 3) ----
__global__ __launch_bounds__(256) void conv_i2(const float* __restrict__ I2,
                                               unsigned char* __restrict__ I2t)
{
    const int idx = blockIdx.x*256 + threadIdx.x;   // 196608
    const int g   = idx & 3;
    const int L   = idx >> 2;                       // ((b*4+kc)*64+row)*96+col
    const int col = L % WW;
    int t = L / WW;
    const int row = t & 63;  t >>= 6;
    const int kc  = t & 3;
    const int b   = t >> 2;
    const int slot = g ^ ((col ^ (col >> 2)) & 3);

    const float* src = I2 + ((size_t)(b*CC + kc*32 + g*8)*HH + row)*WW + col;
    half8 h;
#pragma unroll
    for (int j = 0; j < 8; ++j) h[j] = (_Float16)src[(size_t)j*HWI];
    *(half8*)(I2t + (size_t)L*64 + slot*16) = h;
}

// ---- main: 8px x 2rows per block (M16 = yloc*8+px); 4 rounds K32,
//      SINGLE-buffer {stage; sync; compute; sync} (R4-proven template),
//      40 KB LDS -> all 768 blocks co-resident (3/CU) ----
__global__ __launch_bounds__(256, 4) void corr_kernel(
    const float* __restrict__ I1,
    const unsigned char* __restrict__ I2t,
    const float* __restrict__ flow,
    float* __restrict__ out)
{
    __shared__ __align__(16) unsigned char smem[LDSZ];

    const int tid  = threadIdx.x;
    const int lane = tid & 63;
    const int w    = tid >> 6;      // 4 waves
    const int X  = blockIdx.x * PXB;
    const int y0 = blockIdx.y * 2;
    const int b  = blockIdx.z;
    const int s_tile = min(max(X - 9, 0), WW - TCOL);

    const int fpx = lane & 15;      // MFMA n-lane / m-lane
    const int kg  = lane >> 4;      // k-group

    // ---- hoisted combine identity + flow loads (latency hides under staging) ----
    const int cpx = tid & 7;
    const int oq  = tid >> 3;       // 0..31
    const int xx  = X + cpx;
    float cxv[2], cyv[2];
#pragma unroll
    for (int yloc = 0; yloc < 2; ++yloc) {
        const int yy = y0 + yloc;
        cxv[yloc] = (float)xx + flow[((size_t)(b*2+0)*HH + yy)*WW + xx];
        cyv[yloc] = (float)yy + flow[((size_t)(b*2+1)*HH + yy)*WW + xx];
    }

    // ---- stage A: fp16 [m16][ch128] stride 272B, float4 I1 loads ----
#pragma unroll
    for (int i = 0; i < 2; ++i) {
        const int e   = tid + 256*i;        // 0..511
        const int q   = e & 1;
        const int ch  = (e >> 1) & 127;
        const int myy = e >> 8;
        const float4 v = *(const float4*)&I1[((size_t)(b*CC + ch)*HH + y0 + myy)*WW + X + q*4];
        const float ve[4] = { v.x, v.y, v.z, v.w };
#pragma unroll
        for (int k = 0; k < 4; ++k) {
            const int m = myy*8 + q*4 + k;
            *(_Float16*)(smem + AOFF + m*ASTR + ch*2) = (_Float16)ve[k];
        }
    }

    // ---- hoisted B-fragment offsets: n = r_t*28 + c_t over 35 tiles ----
    int boff[9];
#pragma unroll
    for (int i = 0; i < 9; ++i) {
        const int t   = min(w + 4*i, NCHK - 1);
        const int n   = t*16 + fpx;
        const int r_t = n / TCOL;
        const int c_t = n - r_t*TCOL;
        const int col = s_tile + c_t;
        boff[i] = r_t*ROWB + c_t*64 + ((kg ^ ((col ^ (col >> 2)) & 3)) << 4);
    }
    const int aoff = AOFF + fpx*ASTR + (kg << 4);

    // ---- async staging: round rr (32 ch) -> single buffer; 35 x 1KB DMA chunks ----
    auto stage = [&](int rr) {
#pragma unroll
        for (int i = 0; i < 9; ++i) {
            const int p = w + 4*i;              // wave-uniform
            if (p < NCHK) {
                const int z   = p*1024 + lane*16;
                const int r_t = z / ROWB;           // staged row 0..19
                const int off = z - r_t*ROWB;
                const int c   = off >> 6;
                const int lb  = off & 63;
                const int grow = min(max(y0 - 9 + r_t, 0), HH - 1);
                const unsigned char* src = I2t
                    + ((size_t)(((b*4 + rr)*HH + grow)*WW + s_tile + c))*64 + lb;
                gll16(src, smem + p*1024);
            }
        }
    };

    f32x4 acc[9];
#pragma unroll
    for (int i = 0; i < 9; ++i) acc[i] = (f32x4){0.f,0.f,0.f,0.f};

    stage(0);
    __syncthreads();                 // A visible + DMA(0) drained

#pragma unroll
    for (int r = 0; r < 4; ++r) {
        const half8 af = *(const half8*)(smem + aoff + r*64);
#pragma unroll
        for (int i = 0; i < 9; ++i) {
            if (w + 4*i < NCHK) {               // wave-uniform predicate
                const half8 bf = *(const half8*)(smem + boff[i]);
                acc[i] = __builtin_amdgcn_mfma_f32_16x16x32_f16(af, bf, acc[i], 0, 0, 0);
            }
        }
        __syncthreads();             // all reads of buffer done (lgkm drained per wave)
        if (r < 3) {
            stage(r + 1);            // overwrite buffer
            __syncthreads();         // DMA(r+1) drained for everyone
        }
    }

    // ---- dump D fp16 [c28][r pad21][m pad20] via ds_write_b64 (conflict-free) ----
    _Float16* D = (_Float16*)smem;
#pragma unroll
    for (int i = 0; i < 9; ++i) {
        if (w + 4*i < NCHK) {
            const int n   = (w + 4*i)*16 + fpx;
            const int r_t = n / TCOL;
            const int c_t = n - r_t*TCOL;
            const half4 hv = { (_Float16)acc[i][0], (_Float16)acc[i][1],
                               (_Float16)acc[i][2], (_Float16)acc[i][3] };
            *(half4*)(D + (c_t*21 + r_t)*20 + kg*4) = hv;   // m = kg*4..kg*4+3
        }
    }
    __syncthreads();

    // ---- combine: 81 outputs x (8px, 2rows), shared bilinear weights (R4 math) ----
#pragma unroll
    for (int yloc = 0; yloc < 2; ++yloc) {
        const int yy = y0 + yloc;
        const int m  = yloc*8 + cpx;
        const float cx = cxv[yloc], cy = cyv[yloc];
        const int x0c = (int)floorf(cx);
        const int y0c = (int)floorf(cy);
        const float wx1 = cx - (float)x0c, wx0 = 1.f - wx1;
        const float wy1 = cy - (float)y0c, wy0 = 1.f - wy1;
        float* outb = out + (size_t)b*81*HWI + (size_t)yy*WW + xx;

#pragma unroll
        for (int k = 0; k < 3; ++k) {
            const int o = oq + 32*k;
            if (o < 81) {
                const int dyi = o / 9;
                const int dxi = o - dyi*9;
                const int ix0 = x0c - 4 + dxi;
                const int iy0 = y0c - 4 + dyi;
                const bool vx0 = (ix0   >= 0) && (ix0   < WW);
                const bool vx1 = (ix0+1 >= 0) && (ix0+1 < WW);
                const bool vy0 = (iy0   >= 0) && (iy0   < HH);
                const bool vy1 = (iy0+1 >= 0) && (iy0+1 < HH);
                const int rt  = iy0 - y0 + 9;
                const int r0c = min(max(rt,     0), 19);
                const int r1c = min(max(rt + 1, 0), 19);
                const int c0  = ix0 - s_tile;
                const int c0c = min(max(c0,     0), TCOL-1);
                const int c1c = min(max(c0 + 1, 0), TCOL-1);
                const float d00 = (float)D[(c0c*21 + r0c)*20 + m];
                const float d01 = (float)D[(c1c*21 + r0c)*20 + m];
                const float d10 = (float)D[(c0c*21 + r1c)*20 + m];
                const float d11 = (float)D[(c1c*21 + r1c)*20 + m];
                const float r0 = (vx0 ? wx0*d00 : 0.f) + (vx1 ? wx1*d01 : 0.f);
                const float r1 = (vx0 ? wx0*d10 : 0.f) + (vx1 ? wx1*d11 : 0.f);
                const float v  = (vy0 ? wy0*r0 : 0.f) + (vy1 ? wy1*r1 : 0.f);
                outb[(size_t)o*HWI] = v;
            }
        }
    }
}

extern "C" void kernel_launch(void* const* d_in, const int* in_sizes, int n_in,
                              void* d_out, int out_size, void* d_ws, size_t ws_size,
                              hipStream_t stream)
{
    const float* I1   = (const float*)d_in[0];
    const float* I2   = (const float*)d_in[1];
    const float* flow = (const float*)d_in[2];
    float* out = (float*)d_out;
    unsigned char* I2t = (unsigned char*)d_ws;   // 3,145,728 B

    conv_i2<<<dim3(768), dim3(256), 0, stream>>>(I2, I2t);
    corr_kernel<<<dim3(WW/PXB, HH/2, BB), dim3(256), 0, stream>>>(I1, I2t, flow, out);
}